// Round 2
// baseline (2558.898 us; speedup 1.0000x reference)
//
#include <hip/hip_runtime.h>
#include <cstdint>
#include <cstddef>

#define B_  2048
#define T_  32
#define V_  32000
#define H_  1024
#define A_  1000
#define H3  3072

typedef short short8 __attribute__((ext_vector_type(8)));
typedef float f32x4  __attribute__((ext_vector_type(4)));

typedef __attribute__((address_space(1))) void* as1v;
typedef __attribute__((address_space(3))) void* as3v;

__device__ __forceinline__ unsigned short f2bf(float f) {
  union { float f; unsigned u; } v; v.f = f;
  unsigned r = v.u + 0x7FFFu + ((v.u >> 16) & 1u);   // RNE
  return (unsigned short)(r >> 16);
}

__device__ __forceinline__ float sigmoidf(float x) {
  return 1.f / (1.f + __expf(-x));
}

// ---------------------------------------------------------------- converts
__global__ void conv_bf16(const float* __restrict__ src, unsigned short* __restrict__ dst, int n4) {
  int i = blockIdx.x * blockDim.x + threadIdx.x;
  if (i >= n4) return;
  float4 v = ((const float4*)src)[i];
  ushort4 o;
  o.x = f2bf(v.x); o.y = f2bf(v.y); o.z = f2bf(v.z); o.w = f2bf(v.w);
  ((ushort4*)dst)[i] = o;
}

// h1_w [1000,1024] -> padded bf16 [1024,1024] (rows >= 1000 zero)
__global__ void conv_h1w(const float* __restrict__ src, unsigned short* __restrict__ dst) {
  int i = blockIdx.x * blockDim.x + threadIdx.x;
  if (i >= 1024 * 1024) return;
  int row = i >> 10;
  dst[i] = (row < A_) ? f2bf(src[i]) : (unsigned short)0;
}

__global__ void init_state(float* __restrict__ state, unsigned short* __restrict__ hbf0) {
  int i = blockIdx.x * blockDim.x + threadIdx.x;
  if (i < B_ * H_) { state[i] = 0.f; hbf0[i] = 0; }
}

// alive bitmask per row (bit t = row alive entering step t) + utterance transpose
__global__ void prep(const int* __restrict__ utt, unsigned* __restrict__ alivemask,
                     int* __restrict__ uttT) {
  int b = blockIdx.x * blockDim.x + threadIdx.x;
  if (b >= B_) return;
  unsigned mask = 0, alive = 1;
  #pragma unroll
  for (int t = 0; t < T_; t++) {
    int tk = utt[b * T_ + t];
    mask |= alive << t;
    if (tk == 0) alive = 0;
    uttT[t * B_ + b] = tk;
  }
  alivemask[b] = mask;
}

// ---------------------------------------------------------------- GEMM (m97 pattern)
// C[M,N] = A[M,K] @ W[N,K]^T (+ bias[col]) ; A rows optionally gathered via tok[]
__device__ __forceinline__ void gemm128(
    const unsigned short* __restrict__ Abase,
    const int* __restrict__ tok,          // null -> dense row indexing
    const unsigned short* __restrict__ W,
    const float* __restrict__ bias,       // null -> no bias
    float* __restrict__ C,
    int N, int K,
    unsigned short* lA, unsigned short* lB)
{
  const int tid  = threadIdx.x;
  const int lane = tid & 63;
  const int wv   = tid >> 6;
  const int wr   = (wv >> 1) * 64;
  const int wc   = (wv & 1) * 64;
  const int lm   = lane & 15;
  const int lq   = lane >> 4;
  const int bx   = blockIdx.x, by = blockIdx.y;

  f32x4 acc[4][4];
  #pragma unroll
  for (int i = 0; i < 4; i++)
    #pragma unroll
    for (int j = 0; j < 4; j++)
      acc[i][j] = (f32x4){0.f, 0.f, 0.f, 0.f};

  for (int kt = 0; kt < K; kt += 64) {
    __syncthreads();
    #pragma unroll
    for (int r = 0; r < 4; r++) {
      int li  = r * 256 + tid;
      int row = li >> 3;            // 0..127
      int col = (li & 7) << 3;      // 0,8,..,56 (bf16 elems)
      size_t arow = tok ? (size_t)tok[by * 128 + row] : (size_t)(by * 128 + row);
      const unsigned short* ga = Abase + arow * (size_t)K + kt + col;
      __builtin_amdgcn_global_load_lds((as1v)ga, (as3v)(&lA[(size_t)li * 8]), 16, 0, 0);
      const unsigned short* gb = W + (size_t)(bx * 128 + row) * (size_t)K + kt + col;
      __builtin_amdgcn_global_load_lds((as1v)gb, (as3v)(&lB[(size_t)li * 8]), 16, 0, 0);
    }
    __syncthreads();
    #pragma unroll
    for (int kk = 0; kk < 2; kk++) {
      short8 af[4], bf[4];
      #pragma unroll
      for (int i = 0; i < 4; i++)
        af[i] = *(const short8*)&lA[(wr + i * 16 + lm) * 64 + kk * 32 + lq * 8];
      #pragma unroll
      for (int j = 0; j < 4; j++)
        bf[j] = *(const short8*)&lB[(wc + j * 16 + lm) * 64 + kk * 32 + lq * 8];
      #pragma unroll
      for (int i = 0; i < 4; i++)
        #pragma unroll
        for (int j = 0; j < 4; j++)
          acc[i][j] = __builtin_amdgcn_mfma_f32_16x16x32_bf16(af[i], bf[j], acc[i][j], 0, 0, 0);
    }
  }
  // epilogue: C/D layout col=lane&15, row=quad*4+reg  [verified m89/m91]
  #pragma unroll
  for (int i = 0; i < 4; i++) {
    int row0 = by * 128 + wr + i * 16 + lq * 4;
    #pragma unroll
    for (int j = 0; j < 4; j++) {
      int col = bx * 128 + wc + j * 16 + lm;
      float bv = bias ? bias[col] : 0.f;
      #pragma unroll
      for (int rg = 0; rg < 4; rg++)
        C[(size_t)(row0 + rg) * N + col] = acc[i][j][rg] + bv;
    }
  }
}

// GI chunk GEMM: rows gathered through token ids, bias = b_ih folded in.
__global__ void __launch_bounds__(256) gemm_gi(
    const unsigned short* __restrict__ emb_bf,
    const int* __restrict__ tok,
    const unsigned short* __restrict__ wih_bf,
    const float* __restrict__ bih,
    float* __restrict__ GIc)
{
  __shared__ __align__(16) unsigned short lA[128 * 64];
  __shared__ __align__(16) unsigned short lB[128 * 64];
  gemm128(emb_bf, tok, wih_bf, bih, GIc, H3, H_, lA, lB);
}

__global__ void __launch_bounds__(256) gemm_final(
    const unsigned short* __restrict__ hbf,
    const unsigned short* __restrict__ h1w_bf,
    float* __restrict__ logits)
{
  __shared__ __align__(16) unsigned short lA[128 * 64];
  __shared__ __align__(16) unsigned short lB[128 * 64];
  gemm128(hbf, nullptr, h1w_bf, nullptr, logits, 1024, H_, lA, lB);
}

// ---------------------------------------------------------------- fused GH GEMM + GRU update
// Block (hx, bb): batch rows [bb*128,+128), h-cols [hx*64,+64), all 3 gates.
// 512 threads = 8 waves; wave wv owns rows [wv*16,+16).
__global__ void __launch_bounds__(512) step_fused(
    const float* __restrict__ GIc, int s,              // GI chunk, step-in-chunk
    const unsigned short* __restrict__ hin,            // h_{t-1} bf16 [B,H]
    const unsigned short* __restrict__ whh_bf,         // [3H,H] bf16
    const float* __restrict__ bhh,
    float* __restrict__ state,                         // f32 h (in/out)
    unsigned short* __restrict__ hout,                 // h_t bf16 [B,H]
    const unsigned* __restrict__ amask, int t)
{
  __shared__ __align__(16) unsigned short lA[128 * 64];      // h tile
  __shared__ __align__(16) unsigned short lB[3 * 64 * 64];   // w_hh tiles (3 gates)

  const int tid  = threadIdx.x;
  const int lane = tid & 63;
  const int wv   = tid >> 6;        // 0..7
  const int lm   = lane & 15;
  const int lq   = lane >> 4;
  const int hx   = blockIdx.x;      // 0..15
  const int bb   = blockIdx.y;      // 0..15

  f32x4 acc[3][4];
  #pragma unroll
  for (int g = 0; g < 3; g++)
    #pragma unroll
    for (int j = 0; j < 4; j++)
      acc[g][j] = (f32x4){0.f, 0.f, 0.f, 0.f};

  const int arow = tid >> 3;              // 0..63 within 512-thread staging
  const int acol = (tid & 7) << 3;        // bf16 elem col

  for (int kt = 0; kt < H_; kt += 64) {
    __syncthreads();
    // stage A (h rows): 128x64 bf16, 2 iterations
    #pragma unroll
    for (int it = 0; it < 2; it++) {
      int li  = it * 512 + tid;
      int row = li >> 3;                  // 0..127
      int col = (li & 7) << 3;
      const unsigned short* ga = hin + (size_t)(bb * 128 + row) * H_ + kt + col;
      __builtin_amdgcn_global_load_lds((as1v)ga, (as3v)(&lA[(size_t)li * 8]), 16, 0, 0);
    }
    // stage B (w_hh rows for 3 gates): 3 x 64x64 bf16, 1 iteration each
    #pragma unroll
    for (int g = 0; g < 3; g++) {
      const unsigned short* gb = whh_bf + (size_t)(g * H_ + hx * 64 + arow) * H_ + kt + acol;
      __builtin_amdgcn_global_load_lds((as1v)gb, (as3v)(&lB[(size_t)(g * 512 + tid) * 8]), 16, 0, 0);
    }
    __syncthreads();
    #pragma unroll
    for (int kk = 0; kk < 2; kk++) {
      short8 af = *(const short8*)&lA[(wv * 16 + lm) * 64 + kk * 32 + lq * 8];
      #pragma unroll
      for (int g = 0; g < 3; g++) {
        #pragma unroll
        for (int j = 0; j < 4; j++) {
          short8 bf = *(const short8*)&lB[g * 4096 + (j * 16 + lm) * 64 + kk * 32 + lq * 8];
          acc[g][j] = __builtin_amdgcn_mfma_f32_16x16x32_bf16(af, bf, acc[g][j], 0, 0, 0);
        }
      }
    }
  }

  // epilogue: fused bias + gates + GRU update + alive select
  #pragma unroll
  for (int j = 0; j < 4; j++) {
    int col = hx * 64 + j * 16 + lm;
    float bhr = bhh[col];
    float bhz = bhh[H_ + col];
    float bhn = bhh[2 * H_ + col];
    #pragma unroll
    for (int rg = 0; rg < 4; rg++) {
      int row = bb * 128 + wv * 16 + lq * 4 + rg;
      size_t gi0 = ((size_t)(s * B_ + row)) * H3 + col;
      float gir = GIc[gi0];             // b_ih already folded in
      float giz = GIc[gi0 + H_];
      float gin = GIc[gi0 + 2 * H_];
      float r = sigmoidf(gir + acc[0][j][rg] + bhr);
      float z = sigmoidf(giz + acc[1][j][rg] + bhz);
      float n = tanhf(gin + r * (acc[2][j][rg] + bhn));
      size_t si = (size_t)row * H_ + col;
      float h = state[si];
      float nh = (1.f - z) * n + z * h;
      float o = ((amask[row] >> t) & 1u) ? nh : h;
      state[si] = o;
      hout[si] = f2bf(o);
    }
  }
}

// ---------------------------------------------------------------- softmax head
__global__ void __launch_bounds__(256) softmax_k(const float* __restrict__ logits,
                                                 const float* __restrict__ h1b,
                                                 float* __restrict__ out)
{
  int b = blockIdx.x;
  int tid = threadIdx.x;
  __shared__ float red[8];
  float v[4];
  float lmax = -3.4e38f;
  #pragma unroll
  for (int k = 0; k < 4; k++) {
    int j = tid + k * 256;
    float x = (j < A_) ? (logits[(size_t)b * 1024 + j] + h1b[j]) : -3.4e38f;
    v[k] = x;
    lmax = fmaxf(lmax, x);
  }
  #pragma unroll
  for (int off = 1; off < 64; off <<= 1) lmax = fmaxf(lmax, __shfl_xor(lmax, off, 64));
  if ((tid & 63) == 0) red[tid >> 6] = lmax;
  __syncthreads();
  lmax = fmaxf(fmaxf(red[0], red[1]), fmaxf(red[2], red[3]));
  float s = 0.f;
  #pragma unroll
  for (int k = 0; k < 4; k++) {
    int j = tid + k * 256;
    float e = (j < A_) ? expf(v[k] - lmax) : 0.f;
    v[k] = e; s += e;
  }
  #pragma unroll
  for (int off = 1; off < 64; off <<= 1) s += __shfl_xor(s, off, 64);
  if ((tid & 63) == 0) red[4 + (tid >> 6)] = s;
  __syncthreads();
  s = red[4] + red[5] + red[6] + red[7];
  float inv = 1.f / s;
  #pragma unroll
  for (int k = 0; k < 4; k++) {
    int j = tid + k * 256;
    if (j < A_) out[(size_t)b * A_ + j] = v[k] * inv;
  }
}

// ---------------------------------------------------------------- launch
extern "C" void kernel_launch(void* const* d_in, const int* in_sizes, int n_in,
                              void* d_out, int out_size, void* d_ws, size_t ws_size,
                              hipStream_t stream)
{
  (void)in_sizes; (void)n_in; (void)out_size; (void)ws_size;
  const int*   utt   = (const int*)d_in[0];
  // d_in[1] global_idxes: unused by reference
  const float* emb_w = (const float*)d_in[2];
  const float* w_ih  = (const float*)d_in[3];
  const float* w_hh  = (const float*)d_in[4];
  const float* b_ih  = (const float*)d_in[5];
  const float* b_hh  = (const float*)d_in[6];
  const float* h1_w  = (const float*)d_in[7];
  const float* h1_b  = (const float*)d_in[8];
  float* out = (float*)d_out;

  char* ws = (char*)d_ws;
  size_t off = 0;
  auto alloc = [&](size_t bytes) {
    void* p = ws + off;
    off += (bytes + 255) & ~(size_t)255;
    return p;
  };
  unsigned short* emb_bf = (unsigned short*)alloc((size_t)V_ * H_ * 2);       // 65.5 MB
  unsigned short* wih_bf = (unsigned short*)alloc((size_t)H3 * H_ * 2);       // 6.3 MB
  unsigned short* whh_bf = (unsigned short*)alloc((size_t)H3 * H_ * 2);       // 6.3 MB
  unsigned short* h1w_bf = (unsigned short*)alloc((size_t)1024 * H_ * 2);     // 2.1 MB
  float*          GIc    = (float*)alloc((size_t)8 * B_ * H3 * 4);            // 201 MB (8-step chunk)
  float*          state  = (float*)alloc((size_t)B_ * H_ * 4);                // 8.4 MB
  unsigned short* hbf0   = (unsigned short*)alloc((size_t)B_ * H_ * 2);       // 4.2 MB
  unsigned short* hbf1   = (unsigned short*)alloc((size_t)B_ * H_ * 2);       // 4.2 MB
  float*          logits = (float*)alloc((size_t)B_ * 1024 * 4);              // 8.4 MB
  int*            uttT   = (int*)alloc((size_t)B_ * T_ * 4);
  unsigned*       amask  = (unsigned*)alloc((size_t)B_ * 4);

  int n4 = V_ * H_ / 4;
  conv_bf16<<<(n4 + 255) / 256, 256, 0, stream>>>(emb_w, emb_bf, n4);
  n4 = H3 * H_ / 4;
  conv_bf16<<<(n4 + 255) / 256, 256, 0, stream>>>(w_ih, wih_bf, n4);
  conv_bf16<<<(n4 + 255) / 256, 256, 0, stream>>>(w_hh, whh_bf, n4);
  conv_h1w<<<(1024 * 1024) / 256, 256, 0, stream>>>(h1_w, h1w_bf);
  init_state<<<(B_ * H_) / 256, 256, 0, stream>>>(state, hbf0);
  prep<<<(B_ + 255) / 256, 256, 0, stream>>>(utt, amask, uttT);

  unsigned short* hb[2] = { hbf0, hbf1 };
  dim3 ggi(H3 / 128, (8 * B_) / 128);   // 24 x 128
  dim3 gst(16, 16);                     // hx x bb
  for (int c = 0; c < 4; c++) {
    gemm_gi<<<ggi, 256, 0, stream>>>(emb_bf, uttT + (size_t)c * 8 * B_, wih_bf, b_ih, GIc);
    for (int s = 0; s < 8; s++) {
      int t = c * 8 + s;
      step_fused<<<gst, 512, 0, stream>>>(GIc, s, hb[t & 1], whh_bf, b_hh,
                                          state, hb[(t + 1) & 1], amask, t);
    }
  }
  dim3 gf(1024 / 128, B_ / 128, 1); // 8 x 16
  gemm_final<<<gf, 256, 0, stream>>>(hb[0], h1w_bf, logits);
  softmax_k<<<B_, 256, 0, stream>>>(logits, h1_b, out);
}

// Round 3
// 2282.937 us; speedup vs baseline: 1.1209x; 1.1209x over previous
//
#include <hip/hip_runtime.h>
#include <cstdint>
#include <cstddef>

#define B_  2048
#define T_  32
#define V_  32000
#define H_  1024
#define A_  1000
#define H3  3072

typedef short short8 __attribute__((ext_vector_type(8)));
typedef float f32x4  __attribute__((ext_vector_type(4)));

typedef __attribute__((address_space(1))) void* as1v;
typedef __attribute__((address_space(3))) void* as3v;

__device__ __forceinline__ unsigned short f2bf(float f) {
  union { float f; unsigned u; } v; v.f = f;
  unsigned r = v.u + 0x7FFFu + ((v.u >> 16) & 1u);   // RNE
  return (unsigned short)(r >> 16);
}
__device__ __forceinline__ float bf2f(unsigned short s) {
  union { unsigned u; float f; } v; v.u = ((unsigned)s) << 16;
  return v.f;
}
__device__ __forceinline__ float sigmoidf(float x) {
  return 1.f / (1.f + __expf(-x));
}

// ---------------------------------------------------------------- converts
__global__ void conv_bf16(const float* __restrict__ src, unsigned short* __restrict__ dst, int n4) {
  int i = blockIdx.x * blockDim.x + threadIdx.x;
  if (i >= n4) return;
  float4 v = ((const float4*)src)[i];
  ushort4 o;
  o.x = f2bf(v.x); o.y = f2bf(v.y); o.z = f2bf(v.z); o.w = f2bf(v.w);
  ((ushort4*)dst)[i] = o;
}

// h1_w [1000,1024] -> padded bf16 [1024,1024] (rows >= 1000 zero)
__global__ void conv_h1w(const float* __restrict__ src, unsigned short* __restrict__ dst) {
  int i = blockIdx.x * blockDim.x + threadIdx.x;
  if (i >= 1024 * 1024) return;
  int row = i >> 10;
  dst[i] = (row < A_) ? f2bf(src[i]) : (unsigned short)0;
}

__global__ void init_state(float* __restrict__ state, unsigned short* __restrict__ hbf0) {
  int i = blockIdx.x * blockDim.x + threadIdx.x;
  if (i < B_ * H_) { state[i] = 0.f; hbf0[i] = 0; }
}

// alive bitmask per row + utterance transpose
__global__ void prep(const int* __restrict__ utt, unsigned* __restrict__ alivemask,
                     int* __restrict__ uttT) {
  int b = blockIdx.x * blockDim.x + threadIdx.x;
  if (b >= B_) return;
  unsigned mask = 0, alive = 1;
  #pragma unroll
  for (int t = 0; t < T_; t++) {
    int tk = utt[b * T_ + t];
    mask |= alive << t;
    if (tk == 0) alive = 0;
    uttT[t * B_ + b] = tk;
  }
  alivemask[b] = mask;
}

// gather + f32->bf16 convert: X[row] = bf16(emb_w[tok[row]]), rows dense
__global__ void gather_x(const float* __restrict__ emb, const int* __restrict__ tok,
                         unsigned short* __restrict__ X) {
  int idx = blockIdx.x * 256 + threadIdx.x;
  int row = idx >> 8;
  int c4  = (idx & 255) << 2;
  int tk = tok[row];
  float4 v = *(const float4*)&emb[(size_t)tk * H_ + c4];
  ushort4 o;
  o.x = f2bf(v.x); o.y = f2bf(v.y); o.z = f2bf(v.z); o.w = f2bf(v.w);
  *(ushort4*)&X[(size_t)row * H_ + c4] = o;
}

// ---------------------------------------------------------------- GEMM (m97 pattern, dense)
// C[M,N] = A[M,K] @ W[N,K]^T (+ bias[col])
__device__ __forceinline__ void gemm128(
    const unsigned short* __restrict__ Abase,
    const unsigned short* __restrict__ W,
    const float* __restrict__ bias,       // null -> no bias
    float* __restrict__ C,
    int N, int K,
    unsigned short* lA, unsigned short* lB)
{
  const int tid  = threadIdx.x;
  const int lane = tid & 63;
  const int wv   = tid >> 6;
  const int wr   = (wv >> 1) * 64;
  const int wc   = (wv & 1) * 64;
  const int lm   = lane & 15;
  const int lq   = lane >> 4;
  const int bx   = blockIdx.x, by = blockIdx.y;

  f32x4 acc[4][4];
  #pragma unroll
  for (int i = 0; i < 4; i++)
    #pragma unroll
    for (int j = 0; j < 4; j++)
      acc[i][j] = (f32x4){0.f, 0.f, 0.f, 0.f};

  for (int kt = 0; kt < K; kt += 64) {
    __syncthreads();
    #pragma unroll
    for (int r = 0; r < 4; r++) {
      int li  = r * 256 + tid;
      int row = li >> 3;            // 0..127
      int col = (li & 7) << 3;      // 0,8,..,56 (bf16 elems)
      const unsigned short* ga = Abase + (size_t)(by * 128 + row) * (size_t)K + kt + col;
      __builtin_amdgcn_global_load_lds((as1v)ga, (as3v)(&lA[(size_t)li * 8]), 16, 0, 0);
      const unsigned short* gb = W + (size_t)(bx * 128 + row) * (size_t)K + kt + col;
      __builtin_amdgcn_global_load_lds((as1v)gb, (as3v)(&lB[(size_t)li * 8]), 16, 0, 0);
    }
    __syncthreads();
    #pragma unroll
    for (int kk = 0; kk < 2; kk++) {
      short8 af[4], bf[4];
      #pragma unroll
      for (int i = 0; i < 4; i++)
        af[i] = *(const short8*)&lA[(wr + i * 16 + lm) * 64 + kk * 32 + lq * 8];
      #pragma unroll
      for (int j = 0; j < 4; j++)
        bf[j] = *(const short8*)&lB[(wc + j * 16 + lm) * 64 + kk * 32 + lq * 8];
      #pragma unroll
      for (int i = 0; i < 4; i++)
        #pragma unroll
        for (int j = 0; j < 4; j++)
          acc[i][j] = __builtin_amdgcn_mfma_f32_16x16x32_bf16(af[i], bf[j], acc[i][j], 0, 0, 0);
    }
  }
  // epilogue: C/D layout col=lane&15, row=quad*4+reg  [verified m89/m91]
  #pragma unroll
  for (int i = 0; i < 4; i++) {
    int row0 = by * 128 + wr + i * 16 + lq * 4;
    #pragma unroll
    for (int j = 0; j < 4; j++) {
      int col = bx * 128 + wc + j * 16 + lm;
      float bv = bias ? bias[col] : 0.f;
      #pragma unroll
      for (int rg = 0; rg < 4; rg++)
        C[(size_t)(row0 + rg) * N + col] = acc[i][j][rg] + bv;
    }
  }
}

// GI chunk GEMM over densely gathered X, bias = b_ih folded in.
__global__ void __launch_bounds__(256) gemm_gi(
    const unsigned short* __restrict__ Xc,
    const unsigned short* __restrict__ wih_bf,
    const float* __restrict__ bih,
    float* __restrict__ GIc)
{
  __shared__ __align__(16) unsigned short lA[128 * 64];
  __shared__ __align__(16) unsigned short lB[128 * 64];
  gemm128(Xc, wih_bf, bih, GIc, H3, H_, lA, lB);
}

__global__ void __launch_bounds__(256) gemm_final(
    const unsigned short* __restrict__ hbf,
    const unsigned short* __restrict__ h1w_bf,
    float* __restrict__ logits)
{
  __shared__ __align__(16) unsigned short lA[128 * 64];
  __shared__ __align__(16) unsigned short lB[128 * 64];
  gemm128(hbf, h1w_bf, nullptr, logits, 1024, H_, lA, lB);
}

// ---------------------------------------------------------------- fused GH GEMM + GRU update
// Block (hx, bb): batch rows [bb*64,+64), h-cols [hx*64,+64), all 3 gates.
// 256 threads = 4 waves; wave wv owns rows [wv*16,+16). Grid 16x32 = 512 blocks (2/CU).
__global__ void __launch_bounds__(256) step_fused(
    const float* __restrict__ GIc, int s,              // GI chunk (b_ih folded), step-in-chunk
    const unsigned short* __restrict__ hin,            // h_{t-1} bf16 [B,H]
    const unsigned short* __restrict__ whh_bf,         // [3H,H] bf16
    const float* __restrict__ bhh,
    float* __restrict__ state,                         // f32 h (in/out)
    unsigned short* __restrict__ hout,                 // h_t bf16 [B,H]
    const unsigned* __restrict__ amask, int t)
{
  __shared__ __align__(16) unsigned short lA[64 * 64];       // h tile (8 KB)
  __shared__ __align__(16) unsigned short lB[3 * 64 * 64];   // w_hh tiles (24 KB)

  const int tid  = threadIdx.x;
  const int lane = tid & 63;
  const int wv   = tid >> 6;        // 0..3
  const int lm   = lane & 15;
  const int lq   = lane >> 4;
  const int hx   = blockIdx.x;      // 0..15
  const int bb   = blockIdx.y;      // 0..31

  // ---- prefetch epilogue operands (latency hides under K-loop staging)
  float hreg[4][4];
  float gir[4][4], giz[4][4], gin[4][4];
  #pragma unroll
  for (int j = 0; j < 4; j++) {
    int col = hx * 64 + j * 16 + lm;
    #pragma unroll
    for (int rg = 0; rg < 4; rg++) {
      int row = bb * 64 + wv * 16 + lq * 4 + rg;
      hreg[j][rg] = state[(size_t)row * H_ + col];
      size_t gi0 = ((size_t)(s * B_ + row)) * H3 + col;
      gir[j][rg] = GIc[gi0];
      giz[j][rg] = GIc[gi0 + H_];
      gin[j][rg] = GIc[gi0 + 2 * H_];
    }
  }

  f32x4 acc[3][4];
  #pragma unroll
  for (int g = 0; g < 3; g++)
    #pragma unroll
    for (int j = 0; j < 4; j++)
      acc[g][j] = (f32x4){0.f, 0.f, 0.f, 0.f};

  for (int kt = 0; kt < H_; kt += 64) {
    __syncthreads();
    // stage A (h rows): 64x64 bf16 = 2 x 256 x 16B
    #pragma unroll
    for (int it = 0; it < 2; it++) {
      int li  = it * 256 + tid;
      int row = li >> 3;                  // 0..63
      int col = (li & 7) << 3;
      const unsigned short* ga = hin + (size_t)(bb * 64 + row) * H_ + kt + col;
      __builtin_amdgcn_global_load_lds((as1v)ga, (as3v)(&lA[(size_t)li * 8]), 16, 0, 0);
    }
    // stage B (w_hh rows, 3 gates x 64 rows): 6 x 256 x 16B
    #pragma unroll
    for (int gg = 0; gg < 6; gg++) {
      int li  = gg * 256 + tid;
      int g   = li >> 9;                  // 0..2
      int row = (li >> 3) & 63;
      int col = (li & 7) << 3;
      const unsigned short* gb = whh_bf + (size_t)((g << 10) + hx * 64 + row) * H_ + kt + col;
      __builtin_amdgcn_global_load_lds((as1v)gb, (as3v)(&lB[(size_t)li * 8]), 16, 0, 0);
    }
    __syncthreads();
    #pragma unroll
    for (int kk = 0; kk < 2; kk++) {
      short8 af = *(const short8*)&lA[(wv * 16 + lm) * 64 + kk * 32 + lq * 8];
      #pragma unroll
      for (int g = 0; g < 3; g++) {
        #pragma unroll
        for (int j = 0; j < 4; j++) {
          short8 bf = *(const short8*)&lB[g * 4096 + (j * 16 + lm) * 64 + kk * 32 + lq * 8];
          acc[g][j] = __builtin_amdgcn_mfma_f32_16x16x32_bf16(af, bf, acc[g][j], 0, 0, 0);
        }
      }
    }
  }

  // ---- fused epilogue: bias + gates + GRU update + alive select
  #pragma unroll
  for (int j = 0; j < 4; j++) {
    int col = hx * 64 + j * 16 + lm;
    float bhr = bhh[col];
    float bhz = bhh[H_ + col];
    float bhn = bhh[2 * H_ + col];
    #pragma unroll
    for (int rg = 0; rg < 4; rg++) {
      int row = bb * 64 + wv * 16 + lq * 4 + rg;
      float r = sigmoidf(gir[j][rg] + acc[0][j][rg] + bhr);
      float z = sigmoidf(giz[j][rg] + acc[1][j][rg] + bhz);
      float n = tanhf(gin[j][rg] + r * (acc[2][j][rg] + bhn));
      float h = hreg[j][rg];
      float nh = (1.f - z) * n + z * h;
      float o = ((amask[row] >> t) & 1u) ? nh : h;
      size_t si = (size_t)row * H_ + col;
      state[si] = o;
      hout[si] = f2bf(o);
    }
  }
}

// ---------------------------------------------------------------- softmax head
__global__ void __launch_bounds__(256) softmax_k(const float* __restrict__ logits,
                                                 const float* __restrict__ h1b,
                                                 float* __restrict__ out)
{
  int b = blockIdx.x;
  int tid = threadIdx.x;
  __shared__ float red[8];
  float v[4];
  float lmax = -3.4e38f;
  #pragma unroll
  for (int k = 0; k < 4; k++) {
    int j = tid + k * 256;
    float x = (j < A_) ? (logits[(size_t)b * 1024 + j] + h1b[j]) : -3.4e38f;
    v[k] = x;
    lmax = fmaxf(lmax, x);
  }
  #pragma unroll
  for (int off = 1; off < 64; off <<= 1) lmax = fmaxf(lmax, __shfl_xor(lmax, off, 64));
  if ((tid & 63) == 0) red[tid >> 6] = lmax;
  __syncthreads();
  lmax = fmaxf(fmaxf(red[0], red[1]), fmaxf(red[2], red[3]));
  float s = 0.f;
  #pragma unroll
  for (int k = 0; k < 4; k++) {
    int j = tid + k * 256;
    float e = (j < A_) ? expf(v[k] - lmax) : 0.f;
    v[k] = e; s += e;
  }
  #pragma unroll
  for (int off = 1; off < 64; off <<= 1) s += __shfl_xor(s, off, 64);
  if ((tid & 63) == 0) red[4 + (tid >> 6)] = s;
  __syncthreads();
  s = red[4] + red[5] + red[6] + red[7];
  float inv = 1.f / s;
  #pragma unroll
  for (int k = 0; k < 4; k++) {
    int j = tid + k * 256;
    if (j < A_) out[(size_t)b * A_ + j] = v[k] * inv;
  }
}

// ---------------------------------------------------------------- launch
extern "C" void kernel_launch(void* const* d_in, const int* in_sizes, int n_in,
                              void* d_out, int out_size, void* d_ws, size_t ws_size,
                              hipStream_t stream)
{
  (void)in_sizes; (void)n_in; (void)out_size; (void)ws_size;
  const int*   utt   = (const int*)d_in[0];
  // d_in[1] global_idxes: unused by reference
  const float* emb_w = (const float*)d_in[2];
  const float* w_ih  = (const float*)d_in[3];
  const float* w_hh  = (const float*)d_in[4];
  const float* b_ih  = (const float*)d_in[5];
  const float* b_hh  = (const float*)d_in[6];
  const float* h1_w  = (const float*)d_in[7];
  const float* h1_b  = (const float*)d_in[8];
  float* out = (float*)d_out;

  char* ws = (char*)d_ws;
  size_t off = 0;
  auto alloc = [&](size_t bytes) {
    void* p = ws + off;
    off += (bytes + 255) & ~(size_t)255;
    return p;
  };
  unsigned short* wih_bf = (unsigned short*)alloc((size_t)H3 * H_ * 2);       // 6.3 MB
  unsigned short* whh_bf = (unsigned short*)alloc((size_t)H3 * H_ * 2);       // 6.3 MB
  unsigned short* h1w_bf = (unsigned short*)alloc((size_t)1024 * H_ * 2);     // 2.1 MB
  unsigned short* Xc     = (unsigned short*)alloc((size_t)8 * B_ * H_ * 2);   // 33.5 MB
  float*          GIc    = (float*)alloc((size_t)8 * B_ * H3 * 4);            // 201 MB
  float*          state  = (float*)alloc((size_t)B_ * H_ * 4);                // 8.4 MB
  unsigned short* hbf0   = (unsigned short*)alloc((size_t)B_ * H_ * 2);       // 4.2 MB
  unsigned short* hbf1   = (unsigned short*)alloc((size_t)B_ * H_ * 2);       // 4.2 MB
  float*          logits = (float*)alloc((size_t)B_ * 1024 * 4);              // 8.4 MB
  int*            uttT   = (int*)alloc((size_t)B_ * T_ * 4);
  unsigned*       amask  = (unsigned*)alloc((size_t)B_ * 4);

  int n4 = H3 * H_ / 4;
  conv_bf16<<<(n4 + 255) / 256, 256, 0, stream>>>(w_ih, wih_bf, n4);
  conv_bf16<<<(n4 + 255) / 256, 256, 0, stream>>>(w_hh, whh_bf, n4);
  conv_h1w<<<(1024 * 1024) / 256, 256, 0, stream>>>(h1_w, h1w_bf);
  init_state<<<(B_ * H_) / 256, 256, 0, stream>>>(state, hbf0);
  prep<<<(B_ + 255) / 256, 256, 0, stream>>>(utt, amask, uttT);

  unsigned short* hb[2] = { hbf0, hbf1 };
  const int CROWS = 8 * B_;                 // 16384 rows per chunk
  dim3 ggi(H3 / 128, CROWS / 128);          // 24 x 128
  dim3 gst(16, 32);                         // hx x bb  (512 blocks, 2/CU)
  for (int c = 0; c < 4; c++) {
    gather_x<<<CROWS, 256, 0, stream>>>(emb_w, uttT + (size_t)c * CROWS, Xc);
    gemm_gi<<<ggi, 256, 0, stream>>>(Xc, wih_bf, b_ih, GIc);
    for (int s = 0; s < 8; s++) {
      int t = c * 8 + s;
      step_fused<<<gst, 256, 0, stream>>>(GIc, s, hb[t & 1], whh_bf, b_hh,
                                          state, hb[(t + 1) & 1], amask, t);
    }
  }
  dim3 gf(1024 / 128, B_ / 128, 1); // 8 x 16
  gemm_final<<<gf, 256, 0, stream>>>(hb[0], h1w_bf, logits);
  softmax_k<<<B_, 256, 0, stream>>>(logits, h1_b, out);
}

// Round 4
// 1822.314 us; speedup vs baseline: 1.4042x; 1.2528x over previous
//
#include <hip/hip_runtime.h>
#include <cstdint>
#include <cstddef>

#define B_  2048
#define T_  32
#define V_  32000
#define H_  1024
#define A_  1000
#define H3  3072

typedef short short8 __attribute__((ext_vector_type(8)));
typedef float f32x4  __attribute__((ext_vector_type(4)));

typedef __attribute__((address_space(1))) void* as1v;
typedef __attribute__((address_space(3))) void* as3v;

__device__ __forceinline__ unsigned short f2bf(float f) {
  union { float f; unsigned u; } v; v.f = f;
  unsigned r = v.u + 0x7FFFu + ((v.u >> 16) & 1u);   // RNE
  return (unsigned short)(r >> 16);
}
__device__ __forceinline__ float bf2f(unsigned short s) {
  union { unsigned u; float f; } v; v.u = ((unsigned)s) << 16;
  return v.f;
}
__device__ __forceinline__ float sigmoidf(float x) {
  return 1.f / (1.f + __expf(-x));
}

// ---------------------------------------------------------------- converts
__global__ void conv_bf16(const float* __restrict__ src, unsigned short* __restrict__ dst, int n4) {
  int i = blockIdx.x * blockDim.x + threadIdx.x;
  if (i >= n4) return;
  float4 v = ((const float4*)src)[i];
  ushort4 o;
  o.x = f2bf(v.x); o.y = f2bf(v.y); o.z = f2bf(v.z); o.w = f2bf(v.w);
  ((ushort4*)dst)[i] = o;
}

// h1_w [1000,1024] -> padded bf16 [1024,1024] (rows >= 1000 zero)
__global__ void conv_h1w(const float* __restrict__ src, unsigned short* __restrict__ dst) {
  int i = blockIdx.x * blockDim.x + threadIdx.x;
  if (i >= 1024 * 1024) return;
  int row = i >> 10;
  dst[i] = (row < A_) ? f2bf(src[i]) : (unsigned short)0;
}

__global__ void init_state(float* __restrict__ state, unsigned short* __restrict__ hbf0) {
  int i = blockIdx.x * blockDim.x + threadIdx.x;
  if (i < B_ * H_) { state[i] = 0.f; hbf0[i] = 0; }
}

// alive bitmask per row + utterance transpose
__global__ void prep(const int* __restrict__ utt, unsigned* __restrict__ alivemask,
                     int* __restrict__ uttT) {
  int b = blockIdx.x * blockDim.x + threadIdx.x;
  if (b >= B_) return;
  unsigned mask = 0, alive = 1;
  #pragma unroll
  for (int t = 0; t < T_; t++) {
    int tk = utt[b * T_ + t];
    mask |= alive << t;
    if (tk == 0) alive = 0;
    uttT[t * B_ + b] = tk;
  }
  alivemask[b] = mask;
}

// ---------------------------------------------------------------- EW = bf16(emb @ w_ih^T + b_ih)
// [32000, 3072] bf16. m97-pattern 128x128 tile; grid (24, 250).
__global__ void __launch_bounds__(256) gemm_ew(
    const unsigned short* __restrict__ Abase,   // emb_bf [32000][1024]
    const unsigned short* __restrict__ W,       // wih_bf [3072][1024]
    const float* __restrict__ bias,             // b_ih [3072]
    unsigned short* __restrict__ Cw)            // EW [32000][3072]
{
  __shared__ __align__(16) unsigned short lA[128 * 64];
  __shared__ __align__(16) unsigned short lB[128 * 64];
  const int tid  = threadIdx.x;
  const int lane = tid & 63;
  const int wv   = tid >> 6;
  const int wr   = (wv >> 1) * 64;
  const int wc   = (wv & 1) * 64;
  const int lm   = lane & 15;
  const int lq   = lane >> 4;
  const int bx   = blockIdx.x, by = blockIdx.y;

  f32x4 acc[4][4];
  #pragma unroll
  for (int i = 0; i < 4; i++)
    #pragma unroll
    for (int j = 0; j < 4; j++)
      acc[i][j] = (f32x4){0.f, 0.f, 0.f, 0.f};

  for (int kt = 0; kt < H_; kt += 64) {
    __syncthreads();
    #pragma unroll
    for (int r = 0; r < 4; r++) {
      int li  = r * 256 + tid;
      int row = li >> 3;
      int col = (li & 7) << 3;
      const unsigned short* ga = Abase + (size_t)(by * 128 + row) * H_ + kt + col;
      __builtin_amdgcn_global_load_lds((as1v)ga, (as3v)(&lA[(size_t)li * 8]), 16, 0, 0);
      const unsigned short* gb = W + (size_t)(bx * 128 + row) * H_ + kt + col;
      __builtin_amdgcn_global_load_lds((as1v)gb, (as3v)(&lB[(size_t)li * 8]), 16, 0, 0);
    }
    __syncthreads();
    #pragma unroll
    for (int kk = 0; kk < 2; kk++) {
      short8 af[4], bf[4];
      #pragma unroll
      for (int i = 0; i < 4; i++)
        af[i] = *(const short8*)&lA[(wr + i * 16 + lm) * 64 + kk * 32 + lq * 8];
      #pragma unroll
      for (int j = 0; j < 4; j++)
        bf[j] = *(const short8*)&lB[(wc + j * 16 + lm) * 64 + kk * 32 + lq * 8];
      #pragma unroll
      for (int i = 0; i < 4; i++)
        #pragma unroll
        for (int j = 0; j < 4; j++)
          acc[i][j] = __builtin_amdgcn_mfma_f32_16x16x32_bf16(af[i], bf[j], acc[i][j], 0, 0, 0);
    }
  }
  // epilogue: bias + bf16 store (scalar u16; L2 write-back merges to full lines
  // — round-3 WRITE_SIZE showed full-efficiency strided stores)
  #pragma unroll
  for (int i = 0; i < 4; i++) {
    int row0 = by * 128 + wr + i * 16 + lq * 4;
    #pragma unroll
    for (int j = 0; j < 4; j++) {
      int col = bx * 128 + wc + j * 16 + lm;
      float bv = bias[col];
      #pragma unroll
      for (int rg = 0; rg < 4; rg++)
        Cw[(size_t)(row0 + rg) * H3 + col] = f2bf(acc[i][j][rg] + bv);
    }
  }
}

// ---------------------------------------------------------------- final logits GEMM
__global__ void __launch_bounds__(256) gemm_final(
    const unsigned short* __restrict__ Abase,   // h bf16 [2048][1024]
    const unsigned short* __restrict__ W,       // h1w_bf [1024][1024]
    float* __restrict__ C)                      // logits [2048][1024]
{
  __shared__ __align__(16) unsigned short lA[128 * 64];
  __shared__ __align__(16) unsigned short lB[128 * 64];
  const int tid  = threadIdx.x;
  const int lane = tid & 63;
  const int wv   = tid >> 6;
  const int wr   = (wv >> 1) * 64;
  const int wc   = (wv & 1) * 64;
  const int lm   = lane & 15;
  const int lq   = lane >> 4;
  const int bx   = blockIdx.x, by = blockIdx.y;

  f32x4 acc[4][4];
  #pragma unroll
  for (int i = 0; i < 4; i++)
    #pragma unroll
    for (int j = 0; j < 4; j++)
      acc[i][j] = (f32x4){0.f, 0.f, 0.f, 0.f};

  for (int kt = 0; kt < H_; kt += 64) {
    __syncthreads();
    #pragma unroll
    for (int r = 0; r < 4; r++) {
      int li  = r * 256 + tid;
      int row = li >> 3;
      int col = (li & 7) << 3;
      const unsigned short* ga = Abase + (size_t)(by * 128 + row) * H_ + kt + col;
      __builtin_amdgcn_global_load_lds((as1v)ga, (as3v)(&lA[(size_t)li * 8]), 16, 0, 0);
      const unsigned short* gb = W + (size_t)(bx * 128 + row) * H_ + kt + col;
      __builtin_amdgcn_global_load_lds((as1v)gb, (as3v)(&lB[(size_t)li * 8]), 16, 0, 0);
    }
    __syncthreads();
    #pragma unroll
    for (int kk = 0; kk < 2; kk++) {
      short8 af[4], bf[4];
      #pragma unroll
      for (int i = 0; i < 4; i++)
        af[i] = *(const short8*)&lA[(wr + i * 16 + lm) * 64 + kk * 32 + lq * 8];
      #pragma unroll
      for (int j = 0; j < 4; j++)
        bf[j] = *(const short8*)&lB[(wc + j * 16 + lm) * 64 + kk * 32 + lq * 8];
      #pragma unroll
      for (int i = 0; i < 4; i++)
        #pragma unroll
        for (int j = 0; j < 4; j++)
          acc[i][j] = __builtin_amdgcn_mfma_f32_16x16x32_bf16(af[i], bf[j], acc[i][j], 0, 0, 0);
    }
  }
  #pragma unroll
  for (int i = 0; i < 4; i++) {
    int row0 = by * 128 + wr + i * 16 + lq * 4;
    #pragma unroll
    for (int j = 0; j < 4; j++) {
      int col = bx * 128 + wc + j * 16 + lm;
      #pragma unroll
      for (int rg = 0; rg < 4; rg++)
        C[(size_t)(row0 + rg) * 1024 + col] = acc[i][j][rg];
    }
  }
}

// ---------------------------------------------------------------- fused GH GEMM + GRU update
// Block (hx, bb): batch rows [bb*64,+64), h-cols [hx*64,+64), all 3 gates.
// Gate pre-activations gathered from EW[tok] (b_ih folded in).
__global__ void __launch_bounds__(256) step_fused(
    const unsigned short* __restrict__ EW,             // [V,3H] bf16
    const int* __restrict__ uttT, int t,               // token ids, step
    const unsigned short* __restrict__ hin,            // h_{t-1} bf16 [B,H]
    const unsigned short* __restrict__ whh_bf,         // [3H,H] bf16
    const float* __restrict__ bhh,
    float* __restrict__ state,                         // f32 h (in/out)
    unsigned short* __restrict__ hout,                 // h_t bf16 [B,H]
    const unsigned* __restrict__ amask)
{
  __shared__ __align__(16) unsigned short lA[64 * 64];       // h tile (8 KB)
  __shared__ __align__(16) unsigned short lB[3 * 64 * 64];   // w_hh tiles (24 KB)

  const int tid  = threadIdx.x;
  const int lane = tid & 63;
  const int wv   = tid >> 6;        // 0..3
  const int lm   = lane & 15;
  const int lq   = lane >> 4;
  const int hx   = blockIdx.x;      // 0..15
  const int bb   = blockIdx.y;      // 0..31

  // ---- prefetch epilogue operands (latency hides under K-loop staging)
  int tokr[4];
  #pragma unroll
  for (int rg = 0; rg < 4; rg++)
    tokr[rg] = uttT[t * B_ + bb * 64 + wv * 16 + lq * 4 + rg];

  float hreg[4][4];
  float gir[4][4], giz[4][4], gin[4][4];
  #pragma unroll
  for (int j = 0; j < 4; j++) {
    int col = hx * 64 + j * 16 + lm;
    #pragma unroll
    for (int rg = 0; rg < 4; rg++) {
      int row = bb * 64 + wv * 16 + lq * 4 + rg;
      hreg[j][rg] = state[(size_t)row * H_ + col];
      const unsigned short* ep = EW + (size_t)tokr[rg] * H3 + col;
      gir[j][rg] = bf2f(ep[0]);
      giz[j][rg] = bf2f(ep[H_]);
      gin[j][rg] = bf2f(ep[2 * H_]);
    }
  }

  f32x4 acc[3][4];
  #pragma unroll
  for (int g = 0; g < 3; g++)
    #pragma unroll
    for (int j = 0; j < 4; j++)
      acc[g][j] = (f32x4){0.f, 0.f, 0.f, 0.f};

  for (int kt = 0; kt < H_; kt += 64) {
    __syncthreads();
    // stage A (h rows): 64x64 bf16 = 2 x 256 x 16B
    #pragma unroll
    for (int it = 0; it < 2; it++) {
      int li  = it * 256 + tid;
      int row = li >> 3;                  // 0..63
      int col = (li & 7) << 3;
      const unsigned short* ga = hin + (size_t)(bb * 64 + row) * H_ + kt + col;
      __builtin_amdgcn_global_load_lds((as1v)ga, (as3v)(&lA[(size_t)li * 8]), 16, 0, 0);
    }
    // stage B (w_hh rows, 3 gates x 64 rows): 6 x 256 x 16B
    #pragma unroll
    for (int gg = 0; gg < 6; gg++) {
      int li  = gg * 256 + tid;
      int g   = li >> 9;                  // 0..2
      int row = (li >> 3) & 63;
      int col = (li & 7) << 3;
      const unsigned short* gb = whh_bf + (size_t)((g << 10) + hx * 64 + row) * H_ + kt + col;
      __builtin_amdgcn_global_load_lds((as1v)gb, (as3v)(&lB[(size_t)li * 8]), 16, 0, 0);
    }
    __syncthreads();
    #pragma unroll
    for (int kk = 0; kk < 2; kk++) {
      short8 af = *(const short8*)&lA[(wv * 16 + lm) * 64 + kk * 32 + lq * 8];
      #pragma unroll
      for (int g = 0; g < 3; g++) {
        #pragma unroll
        for (int j = 0; j < 4; j++) {
          short8 bf = *(const short8*)&lB[g * 4096 + (j * 16 + lm) * 64 + kk * 32 + lq * 8];
          acc[g][j] = __builtin_amdgcn_mfma_f32_16x16x32_bf16(af, bf, acc[g][j], 0, 0, 0);
        }
      }
    }
  }

  // ---- fused epilogue: bias + gates + GRU update + alive select
  #pragma unroll
  for (int j = 0; j < 4; j++) {
    int col = hx * 64 + j * 16 + lm;
    float bhr = bhh[col];
    float bhz = bhh[H_ + col];
    float bhn = bhh[2 * H_ + col];
    #pragma unroll
    for (int rg = 0; rg < 4; rg++) {
      int row = bb * 64 + wv * 16 + lq * 4 + rg;
      float r = sigmoidf(gir[j][rg] + acc[0][j][rg] + bhr);
      float z = sigmoidf(giz[j][rg] + acc[1][j][rg] + bhz);
      float n = tanhf(gin[j][rg] + r * (acc[2][j][rg] + bhn));
      float h = hreg[j][rg];
      float nh = (1.f - z) * n + z * h;
      float o = ((amask[row] >> t) & 1u) ? nh : h;
      size_t si = (size_t)row * H_ + col;
      state[si] = o;
      hout[si] = f2bf(o);
    }
  }
}

// ---------------------------------------------------------------- softmax head
__global__ void __launch_bounds__(256) softmax_k(const float* __restrict__ logits,
                                                 const float* __restrict__ h1b,
                                                 float* __restrict__ out)
{
  int b = blockIdx.x;
  int tid = threadIdx.x;
  __shared__ float red[8];
  float v[4];
  float lmax = -3.4e38f;
  #pragma unroll
  for (int k = 0; k < 4; k++) {
    int j = tid + k * 256;
    float x = (j < A_) ? (logits[(size_t)b * 1024 + j] + h1b[j]) : -3.4e38f;
    v[k] = x;
    lmax = fmaxf(lmax, x);
  }
  #pragma unroll
  for (int off = 1; off < 64; off <<= 1) lmax = fmaxf(lmax, __shfl_xor(lmax, off, 64));
  if ((tid & 63) == 0) red[tid >> 6] = lmax;
  __syncthreads();
  lmax = fmaxf(fmaxf(red[0], red[1]), fmaxf(red[2], red[3]));
  float s = 0.f;
  #pragma unroll
  for (int k = 0; k < 4; k++) {
    int j = tid + k * 256;
    float e = (j < A_) ? expf(v[k] - lmax) : 0.f;
    v[k] = e; s += e;
  }
  #pragma unroll
  for (int off = 1; off < 64; off <<= 1) s += __shfl_xor(s, off, 64);
  if ((tid & 63) == 0) red[4 + (tid >> 6)] = s;
  __syncthreads();
  s = red[4] + red[5] + red[6] + red[7];
  float inv = 1.f / s;
  #pragma unroll
  for (int k = 0; k < 4; k++) {
    int j = tid + k * 256;
    if (j < A_) out[(size_t)b * A_ + j] = v[k] * inv;
  }
}

// ---------------------------------------------------------------- launch
extern "C" void kernel_launch(void* const* d_in, const int* in_sizes, int n_in,
                              void* d_out, int out_size, void* d_ws, size_t ws_size,
                              hipStream_t stream)
{
  (void)in_sizes; (void)n_in; (void)out_size; (void)ws_size;
  const int*   utt   = (const int*)d_in[0];
  // d_in[1] global_idxes: unused by reference
  const float* emb_w = (const float*)d_in[2];
  const float* w_ih  = (const float*)d_in[3];
  const float* w_hh  = (const float*)d_in[4];
  const float* b_ih  = (const float*)d_in[5];
  const float* b_hh  = (const float*)d_in[6];
  const float* h1_w  = (const float*)d_in[7];
  const float* h1_b  = (const float*)d_in[8];
  float* out = (float*)d_out;

  char* ws = (char*)d_ws;
  size_t off = 0;
  auto alloc = [&](size_t bytes) {
    void* p = ws + off;
    off += (bytes + 255) & ~(size_t)255;
    return p;
  };
  // emb_bf region (65.5 MB) is dead after gemm_ew; overlay the small
  // per-iteration buffers inside it (written only after gemm_ew completes).
  unsigned short* emb_bf = (unsigned short*)alloc((size_t)V_ * H_ * 2);       // 65.5 MB
  unsigned short* wih_bf = (unsigned short*)alloc((size_t)H3 * H_ * 2);       // 6.3 MB
  unsigned short* EW     = (unsigned short*)alloc((size_t)V_ * H3 * 2);       // 196.6 MB
  unsigned short* whh_bf = (unsigned short*)alloc((size_t)H3 * H_ * 2);       // 6.3 MB
  int*            uttT   = (int*)alloc((size_t)B_ * T_ * 4);
  unsigned*       amask  = (unsigned*)alloc((size_t)B_ * 4);

  char* ov = (char*)emb_bf;           // overlay carve
  unsigned short* h1w_bf = (unsigned short*)(ov);                 // 2.1 MB
  float*          state  = (float*)(ov + 2097152);                // 8.4 MB
  unsigned short* hbf0   = (unsigned short*)(ov + 10485760);      // 4.2 MB
  unsigned short* hbf1   = (unsigned short*)(ov + 14680064);      // 4.2 MB
  float*          logits = (float*)(ov + 18874368);               // 8.4 MB  (ends 27.3 MB < 65.5)

  int n4 = V_ * H_ / 4;
  conv_bf16<<<(n4 + 255) / 256, 256, 0, stream>>>(emb_w, emb_bf, n4);
  n4 = H3 * H_ / 4;
  conv_bf16<<<(n4 + 255) / 256, 256, 0, stream>>>(w_ih, wih_bf, n4);
  conv_bf16<<<(n4 + 255) / 256, 256, 0, stream>>>(w_hh, whh_bf, n4);
  prep<<<(B_ + 255) / 256, 256, 0, stream>>>(utt, amask, uttT);

  dim3 gew(H3 / 128, V_ / 128);       // 24 x 250
  gemm_ew<<<gew, 256, 0, stream>>>(emb_bf, wih_bf, b_ih, EW);

  // emb_bf dead from here; overlay region becomes live
  conv_h1w<<<(1024 * 1024) / 256, 256, 0, stream>>>(h1_w, h1w_bf);
  init_state<<<(B_ * H_) / 256, 256, 0, stream>>>(state, hbf0);

  unsigned short* hb[2] = { hbf0, hbf1 };
  dim3 gst(16, 32);                   // hx x bb  (512 blocks, 2/CU)
  for (int t = 0; t < T_; t++) {
    step_fused<<<gst, 256, 0, stream>>>(EW, uttT, t, hb[t & 1], whh_bf, b_hh,
                                        state, hb[(t + 1) & 1], amask);
  }
  dim3 gf(1024 / 128, B_ / 128);      // 8 x 16
  gemm_final<<<gf, 256, 0, stream>>>(hb[0], h1w_bf, logits);
  softmax_k<<<B_, 256, 0, stream>>>(logits, h1_b, out);
}